// Round 4
// baseline (182.189 us; speedup 1.0000x reference)
//
#include <hip/hip_runtime.h>
#include <math.h>

#define BB 32
#define LL 4096
#define DD 1024
#define CH 64          // l-subtile staged in LDS by k_gemm
#define NCH 32         // l-chunks for k_gemm partials
#define DOTBLK 2048    // persistent k_dot blocks (8 per CU)

// Kernel 1: dlT[l*BB + b] = dot(doc[b,l,:], W[l,:]) + bias[l]
// Persistent grid-stride: 8192 waves, each processes 8 row-PAIRS.
// Rows (b,l),(b,l+1) are contiguous in doc -> each iteration streams
// 8 KB doc + 8 KB W contiguous via 16 float4 loads in flight.
__global__ __launch_bounds__(256) void k_dot(const float* __restrict__ doc,
                                             const float* __restrict__ W,
                                             const float* __restrict__ bias,
                                             float* __restrict__ dlT) {
  const int wid0 = (blockIdx.x * 256 + threadIdx.x) >> 6;  // [0, 8192)
  const int lane = threadIdx.x & 63;

  // 65536 row-pairs: p -> b = p>>11, lp = p&2047, rows l=2*lp, l+1
  for (int p = wid0; p < (BB * LL / 2); p += DOTBLK * 4) {
    const int b = p >> 11;
    const int l = (p & 2047) << 1;
    const float4* dp = reinterpret_cast<const float4*>(doc) +
                       (((size_t)b << 20) + ((size_t)l << 8));
    const float4* wp = reinterpret_cast<const float4*>(W) + ((size_t)l << 8);

    float acc0 = 0.f, acc1 = 0.f;
#pragma unroll
    for (int it = 0; it < 4; ++it) {
      float4 a0 = dp[lane + it * 64];
      float4 w0 = wp[lane + it * 64];
      float4 a1 = dp[256 + lane + it * 64];
      float4 w1 = wp[256 + lane + it * 64];
      acc0 = fmaf(a0.x, w0.x, acc0); acc0 = fmaf(a0.y, w0.y, acc0);
      acc0 = fmaf(a0.z, w0.z, acc0); acc0 = fmaf(a0.w, w0.w, acc0);
      acc1 = fmaf(a1.x, w1.x, acc1); acc1 = fmaf(a1.y, w1.y, acc1);
      acc1 = fmaf(a1.z, w1.z, acc1); acc1 = fmaf(a1.w, w1.w, acc1);
    }
#pragma unroll
    for (int off = 32; off > 0; off >>= 1) {
      acc0 += __shfl_down(acc0, off);
      acc1 += __shfl_down(acc1, off);
    }
    if (lane == 0) {
      dlT[(l << 5) + b]       = acc0 + bias[l];
      dlT[((l + 1) << 5) + b] = acc1 + bias[l + 1];
    }
  }
}

// Kernel 2: part[s][b*LL + j] = sum_{l in chunk s} dlT[l*BB+b] * G[l*LL+j]
// Inner body UNCHANGED from round 3 (it was not the bottleneck).
#define FMA4(A, ds) \
  A.x = fmaf(ds, g.x, A.x); A.y = fmaf(ds, g.y, A.y); \
  A.z = fmaf(ds, g.z, A.z); A.w = fmaf(ds, g.w, A.w);

__global__ __launch_bounds__(256, 4) void k_gemm(const float* __restrict__ dlT,
                                                 const float* __restrict__ G,
                                                 float* __restrict__ part,
                                                 int chunk_l) {
  __shared__ float sdl[CH * BB];    // 8 KB
  const int jt   = blockIdx.x & 15; // 16 j-tiles of 256 columns
  const int s    = blockIdx.x >> 4; // l-chunk
  const int lane = threadIdx.x & 63;
  const int w    = threadIdx.x >> 6;
  const int b0   = w << 3;                    // this wave's b-octet
  const int j0   = (jt << 8) + (lane << 2);   // this thread's 4 columns
  const int l0   = s * chunk_l;

  float4 acc[8];
#pragma unroll
  for (int b = 0; b < 8; ++b) acc[b] = make_float4(0.f, 0.f, 0.f, 0.f);

  for (int t0 = 0; t0 < chunk_l; t0 += CH) {
    {
      const float4* src = reinterpret_cast<const float4*>(dlT + (size_t)(l0 + t0) * BB);
      float4* dst = reinterpret_cast<float4*>(sdl);
      dst[threadIdx.x]       = src[threadIdx.x];
      dst[256 + threadIdx.x] = src[256 + threadIdx.x];
    }
    __syncthreads();

    const float* gb = G + (size_t)(l0 + t0) * LL + j0;
#pragma unroll 8
    for (int il = 0; il < CH; ++il) {
      const float4 g   = *reinterpret_cast<const float4*>(gb + (size_t)il * LL);
      const float4 d01 = *reinterpret_cast<const float4*>(sdl + il * BB + b0);
      const float4 d23 = *reinterpret_cast<const float4*>(sdl + il * BB + b0 + 4);
      FMA4(acc[0], d01.x) FMA4(acc[1], d01.y) FMA4(acc[2], d01.z) FMA4(acc[3], d01.w)
      FMA4(acc[4], d23.x) FMA4(acc[5], d23.y) FMA4(acc[6], d23.z) FMA4(acc[7], d23.w)
    }
    __syncthreads();
  }

  float* po = part + (size_t)s * (BB * LL);
#pragma unroll
  for (int b = 0; b < 8; ++b)
    *reinterpret_cast<float4*>(po + (size_t)(b0 + b) * LL + j0) = acc[b];
}

// Kernel 3: out[i] = sigmoid(sum_s part[s][i])
__global__ __launch_bounds__(256) void k_reduce(const float* __restrict__ part,
                                                float* __restrict__ out,
                                                int nchunks) {
  const int i = blockIdx.x * 256 + threadIdx.x;  // [0, BB*LL)
  float s = 0.f;
#pragma unroll 8
  for (int c = 0; c < nchunks; ++c) s += part[(size_t)c * (BB * LL) + i];
  out[i] = 1.f / (1.f + expf(-s));
}

extern "C" void kernel_launch(void* const* d_in, const int* in_sizes, int n_in,
                              void* d_out, int out_size, void* d_ws, size_t ws_size,
                              hipStream_t stream) {
  const float* doc  = (const float*)d_in[0];  // [B, L, D]
  const float* W    = (const float*)d_in[1];  // [L, D]
  const float* bias = (const float*)d_in[2];  // [L]
  const float* G    = (const float*)d_in[3];  // [L, L]
  float* out = (float*)d_out;                 // [B, L]

  float* dlT = (float*)d_ws;                              // BB*LL floats = 512 KB
  const size_t dl_bytes  = (size_t)BB * LL * sizeof(float);
  const size_t per_chunk = (size_t)BB * LL * sizeof(float);
  float* part = (float*)((char*)d_ws + dl_bytes);

  // l-split: NCH chunks (512 blocks, 2 per CU) if workspace allows.
  int nchunks = NCH;
  size_t avail = ws_size > dl_bytes ? (ws_size - dl_bytes) / per_chunk : 0;
  if ((size_t)nchunks > avail) {
    nchunks = 1;
    while ((size_t)(nchunks * 2) <= avail && nchunks * 2 <= NCH) nchunks *= 2;
  }
  const int chunk_l = LL / nchunks;   // multiple of CH for nchunks <= 64

  k_dot<<<dim3(DOTBLK), dim3(256), 0, stream>>>(doc, W, bias, dlT);
  k_gemm<<<dim3(16 * nchunks), dim3(256), 0, stream>>>(dlT, G, part, chunk_l);
  k_reduce<<<dim3((BB * LL) / 256), dim3(256), 0, stream>>>(part, out, nchunks);
}

// Round 6
// 130.150 us; speedup vs baseline: 1.3998x; 1.3998x over previous
//
#include <hip/hip_runtime.h>
#include <math.h>

#define BB 32
#define LL 4096
#define DD 1024
#define CH 64   // l-subtile staged in LDS by k_gemm

typedef float f4 __attribute__((ext_vector_type(4)));  // native vector: OK for nontemporal builtins

// Kernel 1: dlT[l*BB + b] = dot(doc[b,l,:], W[l,:]) + bias[l]
// One wave per row-PAIR (l, l+1 of one b): 8 KB contiguous doc + 8 KB
// contiguous W per wave, 16 float4 loads in flight, one shuffle-reduce pass
// for two outputs. doc is read nontemporally (streamed once -> don't allocate
// in L2/L3); W stays temporal (re-read 32x across b). 32 adjacent waves share
// the same W row-pair (l-major pair id) -> W from cache.
__global__ __launch_bounds__(256) void k_dot(const float* __restrict__ doc,
                                             const float* __restrict__ W,
                                             const float* __restrict__ bias,
                                             float* __restrict__ dlT) {
  const int wid  = (blockIdx.x * 256 + threadIdx.x) >> 6;  // pair id [0, 65536)
  const int lane = threadIdx.x & 63;
  const int b  = wid & 31;
  const int l  = (wid >> 5) << 1;

  const f4* dp = reinterpret_cast<const f4*>(doc) +
                 (((size_t)b << 20) + ((size_t)l << 8));
  const f4* wp = reinterpret_cast<const f4*>(W) + ((size_t)l << 8);

  f4 a[8], w[8];
#pragma unroll
  for (int it = 0; it < 4; ++it) {
    a[it]     = __builtin_nontemporal_load(&dp[lane + it * 64]);        // row l
    a[it + 4] = __builtin_nontemporal_load(&dp[256 + lane + it * 64]);  // row l+1
  }
#pragma unroll
  for (int it = 0; it < 4; ++it) {
    w[it]     = wp[lane + it * 64];
    w[it + 4] = wp[256 + lane + it * 64];
  }

  float acc0 = 0.f, acc1 = 0.f;
#pragma unroll
  for (int it = 0; it < 4; ++it) {
    acc0 = fmaf(a[it].x, w[it].x, acc0);
    acc0 = fmaf(a[it].y, w[it].y, acc0);
    acc0 = fmaf(a[it].z, w[it].z, acc0);
    acc0 = fmaf(a[it].w, w[it].w, acc0);
    acc1 = fmaf(a[it + 4].x, w[it + 4].x, acc1);
    acc1 = fmaf(a[it + 4].y, w[it + 4].y, acc1);
    acc1 = fmaf(a[it + 4].z, w[it + 4].z, acc1);
    acc1 = fmaf(a[it + 4].w, w[it + 4].w, acc1);
  }
#pragma unroll
  for (int off = 32; off > 0; off >>= 1) {
    acc0 += __shfl_down(acc0, off);
    acc1 += __shfl_down(acc1, off);
  }
  if (lane == 0) {
    dlT[(l << 5) + b]       = acc0 + bias[l];
    dlT[((l + 1) << 5) + b] = acc1 + bias[l + 1];
  }
}

// Kernel 2: part[s][b*LL + j] = sum_{l in chunk s} dlT[l*BB+b] * G[l*LL+j]
// UNCHANGED from round 3.
#define FMA4(A, ds) \
  A.x = fmaf(ds, g.x, A.x); A.y = fmaf(ds, g.y, A.y); \
  A.z = fmaf(ds, g.z, A.z); A.w = fmaf(ds, g.w, A.w);

__global__ __launch_bounds__(256, 4) void k_gemm(const float* __restrict__ dlT,
                                                 const float* __restrict__ G,
                                                 float* __restrict__ part,
                                                 int chunk_l) {
  __shared__ float sdl[CH * BB];    // 8 KB
  const int jt   = blockIdx.x & 15; // 16 j-tiles of 256 columns
  const int s    = blockIdx.x >> 4; // l-chunk
  const int lane = threadIdx.x & 63;
  const int w    = threadIdx.x >> 6;
  const int b0   = w << 3;                    // this wave's b-octet
  const int j0   = (jt << 8) + (lane << 2);   // this thread's 4 columns
  const int l0   = s * chunk_l;

  float4 acc[8];
#pragma unroll
  for (int b = 0; b < 8; ++b) acc[b] = make_float4(0.f, 0.f, 0.f, 0.f);

  for (int t0 = 0; t0 < chunk_l; t0 += CH) {
    {
      const float4* src = reinterpret_cast<const float4*>(dlT + (size_t)(l0 + t0) * BB);
      float4* dst = reinterpret_cast<float4*>(sdl);
      dst[threadIdx.x]       = src[threadIdx.x];
      dst[256 + threadIdx.x] = src[256 + threadIdx.x];
    }
    __syncthreads();

    const float* gb = G + (size_t)(l0 + t0) * LL + j0;
#pragma unroll 8
    for (int il = 0; il < CH; ++il) {
      const float4 g   = *reinterpret_cast<const float4*>(gb + (size_t)il * LL);
      const float4 d01 = *reinterpret_cast<const float4*>(sdl + il * BB + b0);
      const float4 d23 = *reinterpret_cast<const float4*>(sdl + il * BB + b0 + 4);
      FMA4(acc[0], d01.x) FMA4(acc[1], d01.y) FMA4(acc[2], d01.z) FMA4(acc[3], d01.w)
      FMA4(acc[4], d23.x) FMA4(acc[5], d23.y) FMA4(acc[6], d23.z) FMA4(acc[7], d23.w)
    }
    __syncthreads();
  }

  float* po = part + (size_t)s * (BB * LL);
#pragma unroll
  for (int b = 0; b < 8; ++b)
    *reinterpret_cast<float4*>(po + (size_t)(b0 + b) * LL + j0) = acc[b];
}

// Kernel 3: out[i] = sigmoid(sum_s part[s][i]) — UNCHANGED from round 3.
__global__ __launch_bounds__(256) void k_reduce(const float* __restrict__ part,
                                                float* __restrict__ out,
                                                int nchunks) {
  const int i = blockIdx.x * 256 + threadIdx.x;  // [0, BB*LL)
  float s = 0.f;
#pragma unroll 8
  for (int c = 0; c < nchunks; ++c) s += part[(size_t)c * (BB * LL) + i];
  out[i] = 1.f / (1.f + expf(-s));
}

extern "C" void kernel_launch(void* const* d_in, const int* in_sizes, int n_in,
                              void* d_out, int out_size, void* d_ws, size_t ws_size,
                              hipStream_t stream) {
  const float* doc  = (const float*)d_in[0];  // [B, L, D]
  const float* W    = (const float*)d_in[1];  // [L, D]
  const float* bias = (const float*)d_in[2];  // [L]
  const float* G    = (const float*)d_in[3];  // [L, L]
  float* out = (float*)d_out;                 // [B, L]

  float* dlT = (float*)d_ws;                              // BB*LL floats = 512 KB
  const size_t dl_bytes  = (size_t)BB * LL * sizeof(float);
  const size_t per_chunk = (size_t)BB * LL * sizeof(float);
  float* part = (float*)((char*)d_ws + dl_bytes);

  // l-split: 64 chunks (1024 blocks) if workspace allows — as round 3.
  int nchunks = 64;
  size_t avail = ws_size > dl_bytes ? (ws_size - dl_bytes) / per_chunk : 0;
  if ((size_t)nchunks > avail) {
    nchunks = 1;
    while ((size_t)(nchunks * 2) <= avail && nchunks * 2 <= 64) nchunks *= 2;
  }
  const int chunk_l = LL / nchunks;   // multiple of CH for nchunks <= 64

  k_dot<<<dim3((BB * LL / 2) / 4), dim3(256), 0, stream>>>(doc, W, bias, dlT);
  k_gemm<<<dim3(16 * nchunks), dim3(256), 0, stream>>>(dlT, G, part, chunk_l);
  k_reduce<<<dim3((BB * LL) / 256), dim3(256), 0, stream>>>(part, out, nchunks);
}